// Round 2
// baseline (545.909 us; speedup 1.0000x reference)
//
#include <hip/hip_runtime.h>
#include <hip/hip_bf16.h>

#define T_SEQ 2048
#define DIM 4096
#define NH 32
#define NKV 8
#define HD 128
#define QKV_N 6144   // 4096 q + 1024 k + 1024 v

typedef __bf16 bf16x8 __attribute__((ext_vector_type(8)));
typedef float f32x4 __attribute__((ext_vector_type(4)));

__device__ __forceinline__ void storev(float* p, float v) { *p = v; }
__device__ __forceinline__ void storev(__hip_bfloat16* p, float v) { *p = __float2bfloat16(v); }

__device__ __forceinline__ float bf2f(unsigned short u) {
    unsigned int t = ((unsigned int)u) << 16;
    return __builtin_bit_cast(float, t);
}

// async global->LDS, 16B per lane; LDS dest must be wave-uniform base + lane*16
__device__ __forceinline__ void gl_lds16(const __hip_bfloat16* g, __hip_bfloat16* l) {
    __builtin_amdgcn_global_load_lds(
        (const __attribute__((address_space(1))) unsigned int*)g,
        (__attribute__((address_space(3))) unsigned int*)l, 16, 0, 0);
}

// ---------------- cast x (fp32 -> bf16) ----------------
__global__ void cast_x(const float* __restrict__ in, __hip_bfloat16* __restrict__ out, int n) {
    int i = (blockIdx.x * 256 + threadIdx.x) * 4;
    if (i < n) {
        float4 v = *(const float4*)(in + i);
        out[i + 0] = __float2bfloat16(v.x);
        out[i + 1] = __float2bfloat16(v.y);
        out[i + 2] = __float2bfloat16(v.z);
        out[i + 3] = __float2bfloat16(v.w);
    }
}

// ---------------- transpose-cast: out[(c+row_off)][r] = bf16(in[r][c]) ----------------
__global__ void tcast(const float* __restrict__ in, __hip_bfloat16* __restrict__ out,
                      int R, int C, int out_stride, int row_off) {
    __shared__ float tile[64][65];
    int tid = threadIdx.x;
    int r0 = blockIdx.y * 64, c0 = blockIdx.x * 64;
    for (int it = 0; it < 4; it++) {
        int row = (tid >> 4) + 16 * it;
        int c4 = (tid & 15) * 4;
        float4 v = *(const float4*)&in[(size_t)(r0 + row) * C + c0 + c4];
        tile[row][c4 + 0] = v.x;
        tile[row][c4 + 1] = v.y;
        tile[row][c4 + 2] = v.z;
        tile[row][c4 + 3] = v.w;
    }
    __syncthreads();
    for (int it = 0; it < 2; it++) {
        int orow = (tid >> 3) + 32 * it;
        int oc8 = (tid & 7) * 8;
        __hip_bfloat16 tmp[8];
        for (int j = 0; j < 8; j++)
            tmp[j] = __float2bfloat16(tile[oc8 + j][orow]);
        *(uint4*)&out[(size_t)(c0 + orow + row_off) * out_stride + r0 + oc8] = *(uint4*)tmp;
    }
}

// ---------------- bf16 transpose for V: vt[g][d][t] ----------------
__global__ void vtrans(const __hip_bfloat16* __restrict__ qkv, __hip_bfloat16* __restrict__ vt) {
    __shared__ __hip_bfloat16 tile[32][33];
    int tx = threadIdx.x, ty = threadIdx.y;
    int t0 = blockIdx.x * 32, d0 = blockIdx.y * 32, g = blockIdx.z;
    for (int k = 0; k < 4; k++)
        tile[ty + 8 * k][tx] = qkv[(size_t)(t0 + ty + 8 * k) * QKV_N + 5120 + g * HD + d0 + tx];
    __syncthreads();
    for (int k = 0; k < 4; k++)
        vt[(size_t)g * HD * T_SEQ + (size_t)(d0 + ty + 8 * k) * T_SEQ + t0 + tx] =
            tile[tx][ty + 8 * k];
}

// ---------------- RoPE: 8 bf16/thread; q gets 1/sqrt(HD) folded in ----------------
__global__ void rope_kernel(__hip_bfloat16* qkv, const float* __restrict__ cosb,
                            const float* __restrict__ sinb) {
    int idx = blockIdx.x * 256 + threadIdx.x;   // T*640 exactly
    int t = idx / 640;
    int col = (idx % 640) * 8;                  // within [0,5120)
    int i0 = (col & 127) >> 1;
    float f = col < DIM ? 0.08838834764831845f : 1.0f;   // scale q only
    size_t base = (size_t)t * QKV_N + col;
    unsigned short u[8];
    *(uint4*)u = *(const uint4*)&qkv[base];
    float4 cv = *(const float4*)&cosb[t * 64 + i0];
    float4 sv = *(const float4*)&sinb[t * 64 + i0];
    float c[4] = {cv.x, cv.y, cv.z, cv.w}, s[4] = {sv.x, sv.y, sv.z, sv.w};
    __hip_bfloat16 o[8];
    for (int j = 0; j < 4; j++) {
        float a = bf2f(u[2 * j]), b = bf2f(u[2 * j + 1]);
        o[2 * j]     = __float2bfloat16((a * c[j] - b * s[j]) * f);
        o[2 * j + 1] = __float2bfloat16((a * s[j] + b * c[j]) * f);
    }
    *(uint4*)&qkv[base] = *(uint4*)o;
}

// =====================================================================
// 256x256 8-phase GEMM (C = A @ Bt^T), BK=64 as two 32-wide k-halves.
// LDS is fragment-ordered (16B chunk index == lane): ds_read_b128 is
// linear -> conflict-free (measured 0 conflicts in R1).
//
// R2 pipeline restagger: ONE k-half region (A+B = 4 per-wave loads)
// staged per ODD phase, ONE region gated per EVEN phase with vmcnt(8).
// Aging trace (queue oldest-first, entering ph1 = [khi(t), klo(t+1)]):
//   ph1 +khi(t+1)->12 | ph2 vmcnt(8): khi(t) landed   (read ph3-4)
//   ph3 +klo(t+2)->12 | ph4 vmcnt(8): klo(t+1) landed (read ph5-6)
//   ph5 +khi(t+2)->12 | ph6 vmcnt(8): khi(t+1) landed (read ph7-8)
//   ph7 +klo(t+3)->12 | ph8 vmcnt(8): klo(t+2) landed (read next ph1-2)
// Every region: 5 phases issue->gate slack (vs 2 in R1 -> stall).
// WAR: each write issued the phase after its target's last read's
// end-barrier. Tail stages clamp to tile 0 (counts never change).
// =====================================================================
template <typename OutT>
__global__ __launch_bounds__(512, 2) void gemm256(const __hip_bfloat16* __restrict__ A,
                                                  const __hip_bfloat16* __restrict__ Bt,
                                                  OutT* __restrict__ C, int N, int K) {
    // [buf][khalf][g*512 + lane*8] ; g = 16-row group (0..15), 512 bf16 = 64 chunks
    __shared__ __align__(16) __hip_bfloat16 sA[2][2][8192];   // 64 KiB
    __shared__ __align__(16) __hip_bfloat16 sB[2][2][8192];   // 64 KiB
    int tid = threadIdx.x;
    int wave = tid >> 6, lane = tid & 63, quad = lane >> 4, l15 = lane & 15;
    int wm = wave >> 2, wn = wave & 3;          // 2M x 4N wave grid

    // T1 (R2): 2D XCD map — each XCD owns a 4m x 6n rectangle (24 blocks):
    // per-XCD fetch = 4 A-panels (8MB) + 6 B-panels (12MB); per-K-step
    // working set 320KB -> L2-resident, B slices shared 4x within XCD.
    int flat = blockIdx.x;
    int m0, n0;
    if (gridDim.x == 192) {
        int xcd = flat & 7, w = flat >> 3;
        int im = (xcd >> 2) * 4 + (w & 3);      // 0..7
        int in = (xcd & 3) * 6 + (w >> 2);      // 0..23
        m0 = im << 8;
        n0 = in << 8;
    } else {
        int nb = N >> 8;
        m0 = (flat / nb) << 8;
        n0 = (flat % nb) << 8;
    }

    // per-lane gather base: row = base_row + g*16 + l15, k = kcol + quad*8
    const __hip_bfloat16* aThr = A  + (size_t)(m0 + l15) * K + (quad << 3);
    const __hip_bfloat16* bThr = Bt + (size_t)(n0 + l15) * K + (quad << 3);
    int NT = K >> 6;

#define GSTAGE_A(BUF, KS, KCOL) do { \
    gl_lds16(aThr + (size_t)(wave)     * 16 * K + (KCOL), &sA[BUF][KS][(wave) * 512]);     \
    gl_lds16(aThr + (size_t)(wave + 8) * 16 * K + (KCOL), &sA[BUF][KS][(wave + 8) * 512]); \
} while (0)
#define GSTAGE_B(BUF, KS, KCOL) do { \
    gl_lds16(bThr + (size_t)(wave)     * 16 * K + (KCOL), &sB[BUF][KS][(wave) * 512]);     \
    gl_lds16(bThr + (size_t)(wave + 8) * 16 * K + (KCOL), &sB[BUF][KS][(wave + 8) * 512]); \
} while (0)
#define LDFA(BUF, KS, MH) do { _Pragma("unroll") \
    for (int i_ = 0; i_ < 4; i_++) \
        af[i_] = *(const bf16x8*)&sA[BUF][KS][(wm * 8 + (MH) * 4 + i_) * 512 + lane * 8]; } while (0)
#define LDFB(BUF, KS) do { _Pragma("unroll") \
    for (int j_ = 0; j_ < 4; j_++) \
        bfr[j_] = *(const bf16x8*)&sB[BUF][KS][(wn * 4 + j_) * 512 + lane * 8]; } while (0)
#define MFMA16(MH) do { _Pragma("unroll") \
    for (int i_ = 0; i_ < 4; i_++) { _Pragma("unroll") \
        for (int j_ = 0; j_ < 4; j_++) \
            acc[(MH) * 4 + i_][j_] = __builtin_amdgcn_mfma_f32_16x16x32_bf16( \
                af[i_], bfr[j_], acc[(MH) * 4 + i_][j_], 0, 0, 0); } } while (0)
#define PHASE(BUF, KS, MH, LOADB, STAGE_STMT, CHK_STMT) do { \
    bf16x8 af[4]; \
    LDFA(BUF, KS, MH); \
    if (LOADB) LDFB(BUF, KS); \
    STAGE_STMT; \
    CHK_STMT; \
    __builtin_amdgcn_s_barrier(); \
    asm volatile("s_waitcnt lgkmcnt(0)" ::: "memory"); \
    __builtin_amdgcn_sched_barrier(0); \
    __builtin_amdgcn_s_setprio(1); \
    MFMA16(MH); \
    __builtin_amdgcn_s_setprio(0); \
    __builtin_amdgcn_s_barrier(); \
} while (0)

    f32x4 acc[8][4] = {};
    bf16x8 bfr[4];

    // prologue: klo(0), khi(0), klo(1) (12 loads); drain klo(0) -> queue
    // entering loop = [khi(0), klo(1)] = 8 outstanding = steady state.
    GSTAGE_A(0, 0, 0);
    GSTAGE_B(0, 0, 0);
    GSTAGE_A(0, 1, 32);
    GSTAGE_B(0, 1, 32);
    GSTAGE_A(1, 0, 64);
    GSTAGE_B(1, 0, 64);
    asm volatile("s_waitcnt vmcnt(8)" ::: "memory");   // klo(0) landed
    __builtin_amdgcn_s_barrier();

    int niter = K >> 7;   // 2 K-tiles per iteration
    for (int it = 0; it < niter; ++it) {
        int t = it << 1;
        int kh1 = ((t + 1) << 6) + 32;                          // khi(t+1), always valid
        int kl2 = (t + 2 < NT ? (t + 2) : 0) << 6;              // klo(t+2) (tail: dummy)
        int kh2 = ((t + 2 < NT ? (t + 2) : 0) << 6) + 32;       // khi(t+2) (tail: dummy)
        int kl3 = (t + 3 < NT ? (t + 3) : 0) << 6;              // klo(t+3) (tail: dummy)
        PHASE(0, 0, 0, 1, GSTAGE_A(1, 1, kh1); GSTAGE_B(1, 1, kh1), (void)0);
        PHASE(0, 0, 1, 0, (void)0, asm volatile("s_waitcnt vmcnt(8)" ::: "memory"));
        PHASE(0, 1, 0, 1, GSTAGE_A(0, 0, kl2); GSTAGE_B(0, 0, kl2), (void)0);
        PHASE(0, 1, 1, 0, (void)0, asm volatile("s_waitcnt vmcnt(8)" ::: "memory"));
        PHASE(1, 0, 0, 1, GSTAGE_A(0, 1, kh2); GSTAGE_B(0, 1, kh2), (void)0);
        PHASE(1, 0, 1, 0, (void)0, asm volatile("s_waitcnt vmcnt(8)" ::: "memory"));
        PHASE(1, 1, 0, 1, GSTAGE_A(1, 0, kl3); GSTAGE_B(1, 0, kl3), (void)0);
        PHASE(1, 1, 1, 0, (void)0, asm volatile("s_waitcnt vmcnt(8)" ::: "memory"));
    }

    for (int i = 0; i < 8; i++)
        for (int j = 0; j < 4; j++)
            for (int r = 0; r < 4; r++) {
                int row = m0 + wm * 128 + i * 16 + quad * 4 + r;
                int col = n0 + wn * 64 + j * 16 + l15;
                storev(&C[(size_t)row * N + col], acc[i][j][r]);
            }
#undef GSTAGE_A
#undef GSTAGE_B
#undef LDFA
#undef LDFB
#undef MFMA16
#undef PHASE
}

// ---------------- GEMM: C = A @ Bt^T, BK=64 as two 32-wide panels ----------------
// (kept for the output projection: M=2048,N=4096 gives only 128 wgs at 256^2 tiles)
template <typename OutT>
__global__ __launch_bounds__(256, 2) void gemm_bt(const __hip_bfloat16* __restrict__ A,
                                                  const __hip_bfloat16* __restrict__ Bt,
                                                  OutT* __restrict__ C, int M, int N, int K) {
    __shared__ __hip_bfloat16 sA[2][128 * 32];
    __shared__ __hip_bfloat16 sB[2][128 * 32];
    int tid = threadIdx.x;
    int wave = tid >> 6, lane = tid & 63, quad = lane >> 4, l15 = lane & 15;
    int wm = wave >> 1, wn = wave & 1;
    int m0 = blockIdx.y * 128, n0 = blockIdx.x * 128;
    f32x4 acc[4][4] = {};
    for (int k0 = 0; k0 < K; k0 += 64) {
        __syncthreads();
        for (int r = 0; r < 2; r++) {
            int seg = tid + 256 * r;
            int row = seg >> 2, col = (seg & 3) * 8;
            gl_lds16(&A[(size_t)(m0 + row) * K + k0 + col],       &sA[0][row * 32 + col]);
            gl_lds16(&A[(size_t)(m0 + row) * K + k0 + 32 + col],  &sA[1][row * 32 + col]);
            gl_lds16(&Bt[(size_t)(n0 + row) * K + k0 + col],      &sB[0][row * 32 + col]);
            gl_lds16(&Bt[(size_t)(n0 + row) * K + k0 + 32 + col], &sB[1][row * 32 + col]);
        }
        __syncthreads();
        for (int ks = 0; ks < 2; ks++) {
            bf16x8 af[4], bfr[4];
            for (int i = 0; i < 4; i++)
                af[i] = *(const bf16x8*)&sA[ks][(wm * 64 + i * 16 + l15) * 32 + quad * 8];
            for (int j = 0; j < 4; j++)
                bfr[j] = *(const bf16x8*)&sB[ks][(wn * 64 + j * 16 + l15) * 32 + quad * 8];
            for (int i = 0; i < 4; i++)
                for (int j = 0; j < 4; j++)
                    acc[i][j] = __builtin_amdgcn_mfma_f32_16x16x32_bf16(af[i], bfr[j], acc[i][j], 0, 0, 0);
        }
    }
    for (int i = 0; i < 4; i++)
        for (int j = 0; j < 4; j++)
            for (int r = 0; r < 4; r++) {
                int row = m0 + wm * 64 + i * 16 + quad * 4 + r;
                int col = n0 + wn * 64 + j * 16 + l15;
                storev(&C[(size_t)row * N + col], acc[i][j][r]);
            }
}

// ---------------- Flash attention v3: fixed-max softmax (scores bounded) ----------------
// q pre-scaled by 1/sqrt(128) in rope. No running max: p = exp(s), l = plain sum
// accumulated per-lane, reduced once at the end. Masked entries exp to exactly 0.
__global__ __launch_bounds__(256, 2) void attn_kernel(const __hip_bfloat16* __restrict__ qkv,
                                                      const __hip_bfloat16* __restrict__ vt,
                                                      __hip_bfloat16* __restrict__ ctx) {
    __shared__ __align__(16) __hip_bfloat16 sk[64][136];
    __shared__ __align__(16) __hip_bfloat16 sv[128][72];
    __shared__ __align__(16) __hip_bfloat16 sp[4][16][72];
    int tid = threadIdx.x;
    int wave = tid >> 6, lane = tid & 63, quad = lane >> 4, l15 = lane & 15;
    int pair = blockIdx.x, h = blockIdx.y, g = h >> 2;

    for (int rep = 0; rep < 2; rep++) {
        int qb = rep ? (31 - pair) : pair;
        int q0 = qb * 64 + wave * 16;

        bf16x8 qf[4];
        for (int ks = 0; ks < 4; ks++)
            qf[ks] = *(const bf16x8*)&qkv[(size_t)(q0 + l15) * QKV_N + h * HD + ks * 32 + quad * 8];

        f32x4 o[8] = {};
        float l_lane[4] = {0.f, 0.f, 0.f, 0.f};
        int nkt = qb + 1;

        for (int kt = 0; kt < nkt; kt++) {
            __syncthreads();
            for (int rr = 0; rr < 4; rr++) {
                int seg = tid + 256 * rr;
                {
                    int row = seg >> 4, col = (seg & 15) * 8;   // K 64x128
                    *(uint4*)&sk[row][col] =
                        *(const uint4*)&qkv[(size_t)(kt * 64 + row) * QKV_N + DIM + g * HD + col];
                }
                {
                    int row = seg >> 3, col = (seg & 7) * 8;    // Vt 128x64
                    *(uint4*)&sv[row][col] =
                        *(const uint4*)&vt[(size_t)g * HD * T_SEQ + (size_t)row * T_SEQ + kt * 64 + col];
                }
            }
            __syncthreads();
            f32x4 s[4] = {};
            for (int ks = 0; ks < 4; ks++)
                for (int n = 0; n < 4; n++) {
                    bf16x8 kf = *(const bf16x8*)&sk[n * 16 + l15][ks * 32 + quad * 8];
                    s[n] = __builtin_amdgcn_mfma_f32_16x16x32_bf16(qf[ks], kf, s[n], 0, 0, 0);
                }
            bool diag = (kt == qb);
            for (int r = 0; r < 4; r++) {
                float v0 = s[0][r], v1 = s[1][r], v2 = s[2][r], v3 = s[3][r];
                if (diag) {
                    int qrow = q0 + quad * 4 + r;
                    int k0i = kt * 64 + l15;
                    if (k0i      > qrow) v0 = -1e30f;
                    if (k0i + 16 > qrow) v1 = -1e30f;
                    if (k0i + 32 > qrow) v2 = -1e30f;
                    if (k0i + 48 > qrow) v3 = -1e30f;
                }
                float e0 = __expf(v0), e1 = __expf(v1);
                float e2 = __expf(v2), e3 = __expf(v3);
                l_lane[r] += (e0 + e1) + (e2 + e3);
                int qr = quad * 4 + r;
                sp[wave][qr][l15]      = __float2bfloat16(e0);
                sp[wave][qr][16 + l15] = __float2bfloat16(e1);
                sp[wave][qr][32 + l15] = __float2bfloat16(e2);
                sp[wave][qr][48 + l15] = __float2bfloat16(e3);
            }
            // sp is wave-private: wave-level LDS wait suffices (no barrier)
            asm volatile("s_waitcnt lgkmcnt(0)" ::: "memory");
            bf16x8 pf0 = *(const bf16x8*)&sp[wave][l15][quad * 8];
            bf16x8 pf1 = *(const bf16x8*)&sp[wave][l15][32 + quad * 8];
            for (int j = 0; j < 8; j++) {
                bf16x8 vf0 = *(const bf16x8*)&sv[j * 16 + l15][quad * 8];
                bf16x8 vf1 = *(const bf16x8*)&sv[j * 16 + l15][32 + quad * 8];
                o[j] = __builtin_amdgcn_mfma_f32_16x16x32_bf16(pf0, vf0, o[j], 0, 0, 0);
                o[j] = __builtin_amdgcn_mfma_f32_16x16x32_bf16(pf1, vf1, o[j], 0, 0, 0);
            }
        }
        float rl[4];
        for (int r = 0; r < 4; r++) {
            float rs = l_lane[r];
            for (int off = 1; off < 16; off <<= 1) rs += __shfl_xor(rs, off);
            rl[r] = 1.f / rs;
        }
        for (int j = 0; j < 8; j++)
            for (int r = 0; r < 4; r++) {
                int row = q0 + quad * 4 + r;
                int col = h * HD + j * 16 + l15;
                ctx[(size_t)row * DIM + col] = __float2bfloat16(o[j][r] * rl[r]);
            }
    }
}

extern "C" void kernel_launch(void* const* d_in, const int* in_sizes, int n_in,
                              void* d_out, int out_size, void* d_ws, size_t ws_size,
                              hipStream_t stream) {
    const float* x        = (const float*)d_in[0];
    const float* rope_cos = (const float*)d_in[1];
    const float* rope_sin = (const float*)d_in[2];
    const float* wq       = (const float*)d_in[3];
    const float* wk       = (const float*)d_in[4];
    const float* wv       = (const float*)d_in[5];
    const float* wo       = (const float*)d_in[6];
    float* out = (float*)d_out;

    char* ws = (char*)d_ws;
    size_t need = 0;
    need += (size_t)T_SEQ * DIM * 2;
    need += (size_t)QKV_N * DIM * 2;
    need += (size_t)DIM * DIM * 2;
    need += (size_t)T_SEQ * QKV_N * 2;
    need += (size_t)NKV * HD * T_SEQ * 2;
    need += (size_t)T_SEQ * DIM * 2;
    if (ws_size < need) return;

    __hip_bfloat16* x_bf   = (__hip_bfloat16*)ws; ws += (size_t)T_SEQ * DIM * 2;
    __hip_bfloat16* wqkv_t = (__hip_bfloat16*)ws; ws += (size_t)QKV_N * DIM * 2;
    __hip_bfloat16* wo_t   = (__hip_bfloat16*)ws; ws += (size_t)DIM * DIM * 2;
    __hip_bfloat16* qkv    = (__hip_bfloat16*)ws; ws += (size_t)T_SEQ * QKV_N * 2;
    __hip_bfloat16* vt     = (__hip_bfloat16*)ws; ws += (size_t)NKV * HD * T_SEQ * 2;
    __hip_bfloat16* ctx    = (__hip_bfloat16*)ws; ws += (size_t)T_SEQ * DIM * 2;

    cast_x<<<8192, 256, 0, stream>>>(x, x_bf, T_SEQ * DIM);
    tcast<<<dim3(64, 64), 256, 0, stream>>>(wq, wqkv_t, DIM, 4096, 4096, 0);
    tcast<<<dim3(16, 64), 256, 0, stream>>>(wk, wqkv_t, DIM, 1024, 4096, 4096);
    tcast<<<dim3(16, 64), 256, 0, stream>>>(wv, wqkv_t, DIM, 1024, 4096, 5120);
    tcast<<<dim3(64, 64), 256, 0, stream>>>(wo, wo_t, DIM, 4096, 4096, 0);

    // QKV projection: 256^2 8-phase pipeline, grid = 192 (24n x 8m), XCD 2D map
    gemm256<__hip_bfloat16><<<192, 512, 0, stream>>>(x_bf, wqkv_t, qkv, QKV_N, DIM);
    rope_kernel<<<5120, 256, 0, stream>>>(qkv, rope_cos, rope_sin);
    vtrans<<<dim3(64, 4, 8), dim3(32, 8), 0, stream>>>(qkv, vt);
    attn_kernel<<<dim3(16, 32), 256, 0, stream>>>(qkv, vt, ctx);
    gemm_bt<float><<<dim3(32, 16), 256, 0, stream>>>(ctx, wo_t, out, T_SEQ, DIM, DIM);
}

// Round 3
// 495.660 us; speedup vs baseline: 1.1014x; 1.1014x over previous
//
#include <hip/hip_runtime.h>
#include <hip/hip_bf16.h>

#define T_SEQ 2048
#define DIM 4096
#define NH 32
#define NKV 8
#define HD 128
#define QKV_N 6144   // 4096 q + 1024 k + 1024 v

typedef __bf16 bf16x8 __attribute__((ext_vector_type(8)));
typedef float f32x4 __attribute__((ext_vector_type(4)));

__device__ __forceinline__ void storev(float* p, float v) { *p = v; }
__device__ __forceinline__ void storev(__hip_bfloat16* p, float v) { *p = __float2bfloat16(v); }

__device__ __forceinline__ float bf2f(unsigned short u) {
    unsigned int t = ((unsigned int)u) << 16;
    return __builtin_bit_cast(float, t);
}

// async global->LDS, 16B per lane; LDS dest must be wave-uniform base + lane*16
__device__ __forceinline__ void gl_lds16(const __hip_bfloat16* g, __hip_bfloat16* l) {
    __builtin_amdgcn_global_load_lds(
        (const __attribute__((address_space(1))) unsigned int*)g,
        (__attribute__((address_space(3))) unsigned int*)l, 16, 0, 0);
}

// ---------------- cast x (fp32 -> bf16) ----------------
__global__ void cast_x(const float* __restrict__ in, __hip_bfloat16* __restrict__ out, int n) {
    int i = (blockIdx.x * 256 + threadIdx.x) * 4;
    if (i < n) {
        float4 v = *(const float4*)(in + i);
        out[i + 0] = __float2bfloat16(v.x);
        out[i + 1] = __float2bfloat16(v.y);
        out[i + 2] = __float2bfloat16(v.z);
        out[i + 3] = __float2bfloat16(v.w);
    }
}

// ---------------- transpose-cast: out[(c+row_off)][r] = bf16(in[r][c]) ----------------
__global__ void tcast(const float* __restrict__ in, __hip_bfloat16* __restrict__ out,
                      int R, int C, int out_stride, int row_off) {
    __shared__ float tile[64][65];
    int tid = threadIdx.x;
    int r0 = blockIdx.y * 64, c0 = blockIdx.x * 64;
    for (int it = 0; it < 4; it++) {
        int row = (tid >> 4) + 16 * it;
        int c4 = (tid & 15) * 4;
        float4 v = *(const float4*)&in[(size_t)(r0 + row) * C + c0 + c4];
        tile[row][c4 + 0] = v.x;
        tile[row][c4 + 1] = v.y;
        tile[row][c4 + 2] = v.z;
        tile[row][c4 + 3] = v.w;
    }
    __syncthreads();
    for (int it = 0; it < 2; it++) {
        int orow = (tid >> 3) + 32 * it;
        int oc8 = (tid & 7) * 8;
        __hip_bfloat16 tmp[8];
        for (int j = 0; j < 8; j++)
            tmp[j] = __float2bfloat16(tile[oc8 + j][orow]);
        *(uint4*)&out[(size_t)(c0 + orow + row_off) * out_stride + r0 + oc8] = *(uint4*)tmp;
    }
}

// ---------------- bf16 transpose for V: vt[g][d][t] ----------------
__global__ void vtrans(const __hip_bfloat16* __restrict__ qkv, __hip_bfloat16* __restrict__ vt) {
    __shared__ __hip_bfloat16 tile[32][33];
    int tx = threadIdx.x, ty = threadIdx.y;
    int t0 = blockIdx.x * 32, d0 = blockIdx.y * 32, g = blockIdx.z;
    for (int k = 0; k < 4; k++)
        tile[ty + 8 * k][tx] = qkv[(size_t)(t0 + ty + 8 * k) * QKV_N + 5120 + g * HD + d0 + tx];
    __syncthreads();
    for (int k = 0; k < 4; k++)
        vt[(size_t)g * HD * T_SEQ + (size_t)(d0 + ty + 8 * k) * T_SEQ + t0 + tx] =
            tile[tx][ty + 8 * k];
}

// ---------------- RoPE: 8 bf16/thread; q gets 1/sqrt(HD) folded in ----------------
__global__ void rope_kernel(__hip_bfloat16* qkv, const float* __restrict__ cosb,
                            const float* __restrict__ sinb) {
    int idx = blockIdx.x * 256 + threadIdx.x;   // T*640 exactly
    int t = idx / 640;
    int col = (idx % 640) * 8;                  // within [0,5120)
    int i0 = (col & 127) >> 1;
    float f = col < DIM ? 0.08838834764831845f : 1.0f;   // scale q only
    size_t base = (size_t)t * QKV_N + col;
    unsigned short u[8];
    *(uint4*)u = *(const uint4*)&qkv[base];
    float4 cv = *(const float4*)&cosb[t * 64 + i0];
    float4 sv = *(const float4*)&sinb[t * 64 + i0];
    float c[4] = {cv.x, cv.y, cv.z, cv.w}, s[4] = {sv.x, sv.y, sv.z, sv.w};
    __hip_bfloat16 o[8];
    for (int j = 0; j < 4; j++) {
        float a = bf2f(u[2 * j]), b = bf2f(u[2 * j + 1]);
        o[2 * j]     = __float2bfloat16((a * c[j] - b * s[j]) * f);
        o[2 * j + 1] = __float2bfloat16((a * s[j] + b * c[j]) * f);
    }
    *(uint4*)&qkv[base] = *(uint4*)o;
}

// ---------------- GEMM: C = A @ Bt^T, BK=64 as two 32-wide panels ----------------
// Proven structure (R0: 800 TF). 128^2 tile, 32KB LDS -> 2 blocks/CU: the second
// block's waves cover this block's barrier drain (m114 inter-block overlap).
// gemm256 (256^2, 128KB LDS, 1 blk/CU) measured WORSE twice (R1/R2) -> reverted.
template <typename OutT>
__global__ __launch_bounds__(256, 2) void gemm_bt(const __hip_bfloat16* __restrict__ A,
                                                  const __hip_bfloat16* __restrict__ Bt,
                                                  OutT* __restrict__ C, int M, int N, int K) {
    __shared__ __hip_bfloat16 sA[2][128 * 32];
    __shared__ __hip_bfloat16 sB[2][128 * 32];
    int tid = threadIdx.x;
    int wave = tid >> 6, lane = tid & 63, quad = lane >> 4, l15 = lane & 15;
    int wm = wave >> 1, wn = wave & 1;
    int m0 = blockIdx.y * 128, n0 = blockIdx.x * 128;
    f32x4 acc[4][4] = {};
    for (int k0 = 0; k0 < K; k0 += 64) {
        __syncthreads();
        for (int r = 0; r < 2; r++) {
            int seg = tid + 256 * r;
            int row = seg >> 2, col = (seg & 3) * 8;
            gl_lds16(&A[(size_t)(m0 + row) * K + k0 + col],       &sA[0][row * 32 + col]);
            gl_lds16(&A[(size_t)(m0 + row) * K + k0 + 32 + col],  &sA[1][row * 32 + col]);
            gl_lds16(&Bt[(size_t)(n0 + row) * K + k0 + col],      &sB[0][row * 32 + col]);
            gl_lds16(&Bt[(size_t)(n0 + row) * K + k0 + 32 + col], &sB[1][row * 32 + col]);
        }
        __syncthreads();
        for (int ks = 0; ks < 2; ks++) {
            bf16x8 af[4], bfr[4];
            for (int i = 0; i < 4; i++)
                af[i] = *(const bf16x8*)&sA[ks][(wm * 64 + i * 16 + l15) * 32 + quad * 8];
            for (int j = 0; j < 4; j++)
                bfr[j] = *(const bf16x8*)&sB[ks][(wn * 64 + j * 16 + l15) * 32 + quad * 8];
            for (int i = 0; i < 4; i++)
                for (int j = 0; j < 4; j++)
                    acc[i][j] = __builtin_amdgcn_mfma_f32_16x16x32_bf16(af[i], bfr[j], acc[i][j], 0, 0, 0);
        }
    }
    for (int i = 0; i < 4; i++)
        for (int j = 0; j < 4; j++)
            for (int r = 0; r < 4; r++) {
                int row = m0 + wm * 64 + i * 16 + quad * 4 + r;
                int col = n0 + wn * 64 + j * 16 + l15;
                storev(&C[(size_t)row * N + col], acc[i][j][r]);
            }
}

// ---------------- Flash attention v4: double-buffered gl_lds staging ----------------
// q pre-scaled by 1/sqrt(128) in rope. Fixed-max softmax (scores bounded): p=exp(s),
// plain sum, one reduce at the end. Masked entries exp to exactly 0.
//
// R3 change: K/V tiles live in FRAGMENT-ORDERED LDS (16B chunk index == reader lane,
// so every ds_read_b128 is linear/conflict-free) and are staged with global_load_lds
// (linear wave-uniform dest + per-lane gathered global source, rule 21). Tiles are
// double-buffered: next kt's 8 gl_lds16 are issued BEFORE this kt's QK/softmax/PV,
// one vmcnt(0)+barrier per tile (catalog minimum-2-phase recipe) -> HBM/L2 latency
// hides under ~1100 cyc of compute instead of sitting between barriers.
//   skf[buf][s=ks*4+n][c*8+e]  == K [n*16 + (c&15)][ks*32 + (c>>4)*8 + e]
//   svf[buf][u=j*2+hf][c*8+e]  == Vt[j*16 + (c&15)][hf*32 + (c>>4)*8 + e]  (kt-local)
// LDS = 2*16KB + 2*16KB + 9KB = 73KB -> still 2 blocks/CU.
__global__ __launch_bounds__(256, 2) void attn_kernel(const __hip_bfloat16* __restrict__ qkv,
                                                      const __hip_bfloat16* __restrict__ vt,
                                                      __hip_bfloat16* __restrict__ ctx) {
    __shared__ __align__(16) __hip_bfloat16 skf[2][16][512];
    __shared__ __align__(16) __hip_bfloat16 svf[2][16][512];
    __shared__ __align__(16) __hip_bfloat16 sp[4][16][72];
    int tid = threadIdx.x;
    int wave = tid >> 6, lane = tid & 63, quad = lane >> 4, l15 = lane & 15;
    int pair = blockIdx.x, h = blockIdx.y, g = h >> 2;
    int q8 = quad * 8;

    // per-thread invariant source pointers for the 4 subtiles this wave stages
    const __hip_bfloat16* kp[4];
    const __hip_bfloat16* vp[4];
    for (int i = 0; i < 4; i++) {
        int s = wave * 4 + i;
        kp[i] = qkv + (size_t)((s & 3) * 16 + l15) * QKV_N + DIM + g * HD + (s >> 2) * 32 + q8;
        vp[i] = vt + (size_t)g * HD * T_SEQ + (size_t)((s >> 1) * 16 + l15) * T_SEQ + (s & 1) * 32 + q8;
    }

#define ATTN_STAGE(BUF, KT) do { \
    _Pragma("unroll") \
    for (int i_ = 0; i_ < 4; i_++) { \
        int s_ = wave * 4 + i_; \
        gl_lds16(kp[i_] + (size_t)(KT) * 64 * QKV_N, &skf[BUF][s_][0]); \
        gl_lds16(vp[i_] + (KT) * 64,                 &svf[BUF][s_][0]); \
    } \
} while (0)

    for (int rep = 0; rep < 2; rep++) {
        int qb = rep ? (31 - pair) : pair;
        int q0 = qb * 64 + wave * 16;

        bf16x8 qf[4];
        for (int ks = 0; ks < 4; ks++)
            qf[ks] = *(const bf16x8*)&qkv[(size_t)(q0 + l15) * QKV_N + h * HD + ks * 32 + quad * 8];

        f32x4 o[8] = {};
        float l_lane[4] = {0.f, 0.f, 0.f, 0.f};
        int nkt = qb + 1;

        // prologue: stage kt=0 into buf0 (WAR vs previous rep safe: its last reads
        // completed before its final end-of-iter barrier, which precedes this issue)
        ATTN_STAGE(0, 0);
        asm volatile("s_waitcnt vmcnt(0)" ::: "memory");
        __syncthreads();

        for (int kt = 0; kt < nkt; kt++) {
            int cur = kt & 1;
            if (kt + 1 < nkt) ATTN_STAGE(cur ^ 1, kt + 1);   // issue BEFORE compute

            f32x4 s[4] = {};
            for (int ks = 0; ks < 4; ks++)
                for (int n = 0; n < 4; n++) {
                    bf16x8 kf = *(const bf16x8*)&skf[cur][ks * 4 + n][lane * 8];
                    s[n] = __builtin_amdgcn_mfma_f32_16x16x32_bf16(qf[ks], kf, s[n], 0, 0, 0);
                }
            bool diag = (kt == qb);
            for (int r = 0; r < 4; r++) {
                float v0 = s[0][r], v1 = s[1][r], v2 = s[2][r], v3 = s[3][r];
                if (diag) {
                    int qrow = q0 + quad * 4 + r;
                    int k0i = kt * 64 + l15;
                    if (k0i      > qrow) v0 = -1e30f;
                    if (k0i + 16 > qrow) v1 = -1e30f;
                    if (k0i + 32 > qrow) v2 = -1e30f;
                    if (k0i + 48 > qrow) v3 = -1e30f;
                }
                float e0 = __expf(v0), e1 = __expf(v1);
                float e2 = __expf(v2), e3 = __expf(v3);
                l_lane[r] += (e0 + e1) + (e2 + e3);
                int qr = quad * 4 + r;
                sp[wave][qr][l15]      = __float2bfloat16(e0);
                sp[wave][qr][16 + l15] = __float2bfloat16(e1);
                sp[wave][qr][32 + l15] = __float2bfloat16(e2);
                sp[wave][qr][48 + l15] = __float2bfloat16(e3);
            }
            // sp is wave-private: wave-level LDS wait suffices (no barrier)
            asm volatile("s_waitcnt lgkmcnt(0)" ::: "memory");
            bf16x8 pf0 = *(const bf16x8*)&sp[wave][l15][quad * 8];
            bf16x8 pf1 = *(const bf16x8*)&sp[wave][l15][32 + quad * 8];
            for (int j = 0; j < 8; j++) {
                bf16x8 vf0 = *(const bf16x8*)&svf[cur][j * 2 + 0][lane * 8];
                bf16x8 vf1 = *(const bf16x8*)&svf[cur][j * 2 + 1][lane * 8];
                o[j] = __builtin_amdgcn_mfma_f32_16x16x32_bf16(pf0, vf0, o[j], 0, 0, 0);
                o[j] = __builtin_amdgcn_mfma_f32_16x16x32_bf16(pf1, vf1, o[j], 0, 0, 0);
            }
            // next tile's loads had the whole phase to fly; drain own, then barrier
            asm volatile("s_waitcnt vmcnt(0)" ::: "memory");
            __syncthreads();
        }
        float rl[4];
        for (int r = 0; r < 4; r++) {
            float rs = l_lane[r];
            for (int off = 1; off < 16; off <<= 1) rs += __shfl_xor(rs, off);
            rl[r] = 1.f / rs;
        }
        for (int j = 0; j < 8; j++)
            for (int r = 0; r < 4; r++) {
                int row = q0 + quad * 4 + r;
                int col = h * HD + j * 16 + l15;
                ctx[(size_t)row * DIM + col] = __float2bfloat16(o[j][r] * rl[r]);
            }
    }
#undef ATTN_STAGE
}

extern "C" void kernel_launch(void* const* d_in, const int* in_sizes, int n_in,
                              void* d_out, int out_size, void* d_ws, size_t ws_size,
                              hipStream_t stream) {
    const float* x        = (const float*)d_in[0];
    const float* rope_cos = (const float*)d_in[1];
    const float* rope_sin = (const float*)d_in[2];
    const float* wq       = (const float*)d_in[3];
    const float* wk       = (const float*)d_in[4];
    const float* wv       = (const float*)d_in[5];
    const float* wo       = (const float*)d_in[6];
    float* out = (float*)d_out;

    char* ws = (char*)d_ws;
    size_t need = 0;
    need += (size_t)T_SEQ * DIM * 2;
    need += (size_t)QKV_N * DIM * 2;
    need += (size_t)DIM * DIM * 2;
    need += (size_t)T_SEQ * QKV_N * 2;
    need += (size_t)NKV * HD * T_SEQ * 2;
    need += (size_t)T_SEQ * DIM * 2;
    if (ws_size < need) return;

    __hip_bfloat16* x_bf   = (__hip_bfloat16*)ws; ws += (size_t)T_SEQ * DIM * 2;
    __hip_bfloat16* wqkv_t = (__hip_bfloat16*)ws; ws += (size_t)QKV_N * DIM * 2;
    __hip_bfloat16* wo_t   = (__hip_bfloat16*)ws; ws += (size_t)DIM * DIM * 2;
    __hip_bfloat16* qkv    = (__hip_bfloat16*)ws; ws += (size_t)T_SEQ * QKV_N * 2;
    __hip_bfloat16* vt     = (__hip_bfloat16*)ws; ws += (size_t)NKV * HD * T_SEQ * 2;
    __hip_bfloat16* ctx    = (__hip_bfloat16*)ws; ws += (size_t)T_SEQ * DIM * 2;

    cast_x<<<8192, 256, 0, stream>>>(x, x_bf, T_SEQ * DIM);
    tcast<<<dim3(64, 64), 256, 0, stream>>>(wq, wqkv_t, DIM, 4096, 4096, 0);
    tcast<<<dim3(16, 64), 256, 0, stream>>>(wk, wqkv_t, DIM, 1024, 4096, 4096);
    tcast<<<dim3(16, 64), 256, 0, stream>>>(wv, wqkv_t, DIM, 1024, 4096, 5120);
    tcast<<<dim3(64, 64), 256, 0, stream>>>(wo, wo_t, DIM, 4096, 4096, 0);

    gemm_bt<__hip_bfloat16><<<dim3(48, 16), 256, 0, stream>>>(x_bf, wqkv_t, qkv, T_SEQ, QKV_N, DIM);
    rope_kernel<<<5120, 256, 0, stream>>>(qkv, rope_cos, rope_sin);
    vtrans<<<dim3(64, 4, 8), dim3(32, 8), 0, stream>>>(qkv, vt);
    attn_kernel<<<dim3(16, 32), 256, 0, stream>>>(qkv, vt, ctx);
    gemm_bt<float><<<dim3(32, 16), 256, 0, stream>>>(ctx, wo_t, out, T_SEQ, DIM, DIM);
}